// Round 9
// baseline (200.280 us; speedup 1.0000x reference)
//
#include <hip/hip_runtime.h>
#include <hip/hip_bf16.h>

#define BATCH 8192
#define NVERT 778
#define NVP   832     // vertex pad: 13 tiles of 64
#define NJ 16
#define KDIM 160      // 135 pose_feature + 10 betas + 1 const + 14 zero-pad
#define ASTR 196      // Abuf row stride in floats (192 used + 4 pad) = 49 x 16B chunks

typedef __attribute__((ext_vector_type(8))) short short8v;
typedef __attribute__((ext_vector_type(4))) float f32x4;
typedef const __attribute__((address_space(1))) unsigned int* gas1_t;
typedef __attribute__((address_space(3))) unsigned int* las3_t;

static __device__ __forceinline__ unsigned short f2bf(float f) {
    unsigned int u = __float_as_uint(f);
    unsigned int r = (u + 0x7FFFu + ((u >> 16) & 1u)) >> 16;  // RNE
    return (unsigned short)r;
}

// ---------------------------------------------------------------- K0: fold J_regressor
__global__ __launch_bounds__(64) void k_pre(const float* __restrict__ tmpl,
                                            const float* __restrict__ shd,
                                            const float* __restrict__ Jreg,
                                            float* __restrict__ JS,
                                            float* __restrict__ Jb)
{
    int e = blockIdx.x, l = threadIdx.x;
    float s = 0.0f;
    if (e < 480) {
        int j = e / 30, k = (e / 10) % 3, q = e % 10;
        for (int v = l; v < NVERT; v += 64) s += Jreg[j * NVERT + v] * shd[v * 30 + k * 10 + q];
    } else {
        int i = e - 480, j = i / 3, k = i % 3;
        for (int v = l; v < NVERT; v += 64) s += Jreg[j * NVERT + v] * tmpl[v * 3 + k];
    }
#pragma unroll
    for (int off = 32; off > 0; off >>= 1) s += __shfl_down(s, off, 64);
    if (l == 0) { if (e < 480) JS[e] = s; else Jb[e - 480] = s; }
}

// ---------------------------------------------------------------- K1: Rodrigues + X pack
__global__ __launch_bounds__(256) void k_rodr(const float* __restrict__ pose,
                                              const float* __restrict__ betas,
                                              float* __restrict__ rot,
                                              short* __restrict__ X)
{
    int t = blockIdx.x * 256 + threadIdx.x;
    if (t >= BATCH * NJ) return;
    int b = t >> 4, j = t & 15;
    const float* p = pose + b * 48 + j * 3;
    float x = p[0], y = p[1], z = p[2];
    float ax = x + 1e-8f, ay = y + 1e-8f, az = z + 1e-8f;
    float ang = sqrtf(ax * ax + ay * ay + az * az);
    float inv = 1.0f / ang;
    float a = x * inv, bb = y * inv, cc = z * inv;
    float sn = sinf(ang), co = cosf(ang);
    float oc = 1.0f - co;
    float R[9];
    R[0] = 1.0f - oc * (bb * bb + cc * cc);
    R[1] = -sn * cc + oc * a * bb;
    R[2] =  sn * bb + oc * a * cc;
    R[3] =  sn * cc + oc * a * bb;
    R[4] = 1.0f - oc * (a * a + cc * cc);
    R[5] = -sn * a + oc * bb * cc;
    R[6] = -sn * bb + oc * a * cc;
    R[7] =  sn * a + oc * bb * cc;
    R[8] = 1.0f - oc * (a * a + bb * bb);

    float* Rg = rot + b * 144 + j * 9;
#pragma unroll
    for (int m = 0; m < 9; ++m) Rg[m] = R[m];

    short* Xb = X + (size_t)b * KDIM;
    if (j > 0) {
        int base = (j - 1) * 9;
#pragma unroll
        for (int m = 0; m < 9; ++m) {
            float d = (m == 0 || m == 4 || m == 8) ? 1.0f : 0.0f;
            Xb[base + m] = (short)f2bf(R[m] - d);
        }
    } else {
#pragma unroll
        for (int l = 0; l < 10; ++l) Xb[135 + l] = (short)f2bf(betas[b * 10 + l]);
        Xb[145] = (short)0x3F80;  // 1.0 bf16
#pragma unroll
        for (int q = 146; q < 160; ++q) Xb[q] = 0;
    }
}

// ---------------------------------------------------------------- K2: kinematic chain per b
__global__ __launch_bounds__(64) void k_chain(
    const float* __restrict__ betas, const float* __restrict__ rot,
    const float* __restrict__ JS, const float* __restrict__ Jb,
    float* __restrict__ Abuf, float* __restrict__ jout)
{
    int b = blockIdx.x * 64 + threadIdx.x;
    if (b >= BATCH) return;
    float be[10];
#pragma unroll
    for (int l = 0; l < 10; ++l) be[l] = betas[b * 10 + l];

    const float* rb = rot + b * 144;
    float* Ab = Abuf + (size_t)b * ASTR;
    float* jo = jout + b * 48;

    float j0[3];
#pragma unroll
    for (int k = 0; k < 3; ++k) {
        float s = Jb[k];
#pragma unroll
        for (int l = 0; l < 10; ++l) s += JS[k * 10 + l] * be[l];
        j0[k] = s;
    }
    float R0[9];
#pragma unroll
    for (int m = 0; m < 9; ++m) R0[m] = rb[m];

#pragma unroll
    for (int r = 0; r < 3; ++r) {
        Ab[r * 4 + 0] = R0[r * 3 + 0];
        Ab[r * 4 + 1] = R0[r * 3 + 1];
        Ab[r * 4 + 2] = R0[r * 3 + 2];
        Ab[r * 4 + 3] = j0[r] - (R0[r * 3 + 0] * j0[0] + R0[r * 3 + 1] * j0[1] + R0[r * 3 + 2] * j0[2]);
        jo[r] = j0[r];
    }

#pragma unroll
    for (int c = 0; c < 5; ++c) {
        float Gp[12];
#pragma unroll
        for (int r = 0; r < 3; ++r) {
            Gp[r * 4 + 0] = R0[r * 3 + 0];
            Gp[r * 4 + 1] = R0[r * 3 + 1];
            Gp[r * 4 + 2] = R0[r * 3 + 2];
            Gp[r * 4 + 3] = j0[r];
        }
        float jp[3] = { j0[0], j0[1], j0[2] };
#pragma unroll
        for (int s3 = 0; s3 < 3; ++s3) {
            int j = 3 * c + 1 + s3;
            float jj[3];
#pragma unroll
            for (int k = 0; k < 3; ++k) {
                float s = Jb[j * 3 + k];
#pragma unroll
                for (int l = 0; l < 10; ++l) s += JS[(j * 3 + k) * 10 + l] * be[l];
                jj[k] = s;
            }
            float R[9];
#pragma unroll
            for (int m = 0; m < 9; ++m) R[m] = rb[j * 9 + m];
            float rel[3] = { jj[0] - jp[0], jj[1] - jp[1], jj[2] - jp[2] };
            float Gc[12];
#pragma unroll
            for (int r = 0; r < 3; ++r) {
#pragma unroll
                for (int cc = 0; cc < 3; ++cc)
                    Gc[r * 4 + cc] = Gp[r * 4 + 0] * R[cc] + Gp[r * 4 + 1] * R[3 + cc] + Gp[r * 4 + 2] * R[6 + cc];
                Gc[r * 4 + 3] = Gp[r * 4 + 0] * rel[0] + Gp[r * 4 + 1] * rel[1] + Gp[r * 4 + 2] * rel[2] + Gp[r * 4 + 3];
            }
#pragma unroll
            for (int r = 0; r < 3; ++r) {
                Ab[j * 12 + r * 4 + 0] = Gc[r * 4 + 0];
                Ab[j * 12 + r * 4 + 1] = Gc[r * 4 + 1];
                Ab[j * 12 + r * 4 + 2] = Gc[r * 4 + 2];
                Ab[j * 12 + r * 4 + 3] = Gc[r * 4 + 3] - (Gc[r * 4 + 0] * jj[0] + Gc[r * 4 + 1] * jj[1] + Gc[r * 4 + 2] * jj[2]);
                jo[j * 3 + r] = Gc[r * 4 + 3];
            }
#pragma unroll
            for (int m = 0; m < 12; ++m) Gp[m] = Gc[m];
            jp[0] = jj[0]; jp[1] = jj[1]; jp[2] = jj[2];
        }
    }
}

// ---------------------------------------------------------------- K3: pack Wt3 [3][NVP][KDIM] bf16
__global__ __launch_bounds__(256) void k_pack3(const float* __restrict__ posed,
                                               const float* __restrict__ shd,
                                               const float* __restrict__ tmpl,
                                               short* __restrict__ Wt3)
{
    int e = blockIdx.x * 256 + threadIdx.x;   // ((p*NVP + v)*KDIM + k)
    if (e >= 3 * NVP * KDIM) return;
    int k = e % KDIM, pv = e / KDIM;
    int v = pv % NVP, p = pv / NVP;
    float val = 0.0f;
    if (v < NVERT) {
        int n = v * 3 + p;
        if (k < 135)       val = posed[(size_t)k * (NVERT * 3) + n];
        else if (k < 145)  val = shd[v * 30 + p * 10 + (k - 135)];
        else if (k == 145) val = tmpl[n];
    }
    Wt3[e] = (short)f2bf(val);
}

// ---------------------------------------------------------------- K4: fused MFMA GEMM + LBS
// BISECT vs round 7: ONLY change = ph1 LDS removed; MFMA operands direct from
// global (X row wave-private, Wt3 L2-resident). A_s staging issued at entry,
// drains at the single barrier. Everything else byte-identical to round 7.
// LDS: A_s[64][196] + w_s[64][17] = 54,528 B -> 3 blocks/CU.
__global__ __launch_bounds__(256, 2) void k_fused(
    const short* __restrict__ X, const short* __restrict__ Wt3,
    const float* __restrict__ Abuf, const float* __restrict__ wgt,
    float* __restrict__ out)
{
    __shared__ __attribute__((aligned(16))) char smem[54528];
    float* A_s = (float*)smem;                 // [64][196] = 50,176 B
    float* w_s = (float*)(smem + 50176);       // [64][17]  =  4,352 B

    const int tid = threadIdx.x;
    const int wid = tid >> 6, lane = tid & 63;
    const int lm = lane & 15, lk = lane >> 4;
    const int v0 = blockIdx.x * 64;
    const int b0 = blockIdx.y * 64;

    // ---- A_s staging issued NOW (async; drains at the single barrier) ----
    for (int c0 = wid * 64; c0 < 3136; c0 += 256) {
        int c = c0 + lane;
        const float* src = Abuf + (size_t)(b0 + c / 49) * ASTR + (c % 49) * 4;
        __builtin_amdgcn_global_load_lds((gas1_t)(const void*)src,
                                         (las3_t)(void*)(smem + c0 * 16), 16, 0, 0);
    }
    // w_s fill: exact round-7 layout [64][17]
    for (int e = tid; e < 64 * 17; e += 256) {
        int vi = e / 17, jj = e % 17;
        float val = (jj < 16 && (v0 + vi) < NVERT) ? wgt[(v0 + vi) * 16 + jj] : 0.0f;
        w_s[e] = val;
    }

    // ---- MFMA from global: acc[p][vi], K=160 in 5 steps of 32 ----
    f32x4 acc[3][4];
#pragma unroll
    for (int p = 0; p < 3; ++p)
#pragma unroll
        for (int vi = 0; vi < 4; ++vi)
            acc[p][vi] = (f32x4){0.0f, 0.0f, 0.0f, 0.0f};

    const short* Xrow = X + (size_t)(b0 + wid * 16 + lm) * KDIM;
#pragma unroll
    for (int ks = 0; ks < 5; ++ks) {
        int kg = ks * 4 + lk;
        short8v a = *(const short8v*)&Xrow[kg * 8];
        short8v bf[3][4];
#pragma unroll
        for (int p = 0; p < 3; ++p)
#pragma unroll
            for (int vi = 0; vi < 4; ++vi)
                bf[p][vi] = *(const short8v*)&Wt3[(size_t)(p * NVP + v0 + vi * 16 + lm) * KDIM + kg * 8];
#pragma unroll
        for (int p = 0; p < 3; ++p)
#pragma unroll
            for (int vi = 0; vi < 4; ++vi)
                acc[p][vi] = __builtin_amdgcn_mfma_f32_16x16x32_bf16(a, bf[p][vi], acc[p][vi], 0, 0, 0);
    }
    __syncthreads();   // drains staging vmcnt + w_s lgkmcnt for all waves

    // ---- LBS blend: exact round-7 loop structure ----
    float o[4][4][3];
#pragma unroll
    for (int r = 0; r < 4; ++r)
#pragma unroll
        for (int vi = 0; vi < 4; ++vi)
            o[r][vi][0] = o[r][vi][1] = o[r][vi][2] = 0.0f;

    for (int j = 0; j < 16; ++j) {
        float wj[4];
#pragma unroll
        for (int vi = 0; vi < 4; ++vi) wj[vi] = w_s[(vi * 16 + lm) * 17 + j];
#pragma unroll
        for (int r = 0; r < 4; ++r) {
            const float* Ar = &A_s[(wid * 16 + lk * 4 + r) * ASTR + j * 12];
            f32x4 R0 = *(const f32x4*)(Ar);
            f32x4 R1 = *(const f32x4*)(Ar + 4);
            f32x4 R2 = *(const f32x4*)(Ar + 8);
#pragma unroll
            for (int vi = 0; vi < 4; ++vi) {
                float x = acc[0][vi][r], y = acc[1][vi][r], z = acc[2][vi][r];
                float t0 = fmaf(R0[0], x, fmaf(R0[1], y, fmaf(R0[2], z, R0[3])));
                float t1 = fmaf(R1[0], x, fmaf(R1[1], y, fmaf(R1[2], z, R1[3])));
                float t2 = fmaf(R2[0], x, fmaf(R2[1], y, fmaf(R2[2], z, R2[3])));
                o[r][vi][0] = fmaf(wj[vi], t0, o[r][vi][0]);
                o[r][vi][1] = fmaf(wj[vi], t1, o[r][vi][1]);
                o[r][vi][2] = fmaf(wj[vi], t2, o[r][vi][2]);
            }
        }
    }

    // ---- store: exact round-7 ----
#pragma unroll
    for (int r = 0; r < 4; ++r) {
        int b = b0 + wid * 16 + lk * 4 + r;
#pragma unroll
        for (int vi = 0; vi < 4; ++vi) {
            int v = v0 + vi * 16 + lm;
            if (v < NVERT) {
                float* op = out + ((size_t)b * NVERT + v) * 3;
                op[0] = o[r][vi][0]; op[1] = o[r][vi][1]; op[2] = o[r][vi][2];
            }
        }
    }
}

// ----------------------------------------------------------------
extern "C" void kernel_launch(void* const* d_in, const int* in_sizes, int n_in,
                              void* d_out, int out_size, void* d_ws, size_t ws_size,
                              hipStream_t stream)
{
    (void)in_sizes; (void)n_in; (void)out_size; (void)ws_size;
    const float* betas = (const float*)d_in[0];
    const float* pose  = (const float*)d_in[1];
    const float* tmpl  = (const float*)d_in[2];
    const float* shd   = (const float*)d_in[3];
    const float* posed = (const float*)d_in[4];
    const float* Jreg  = (const float*)d_in[5];
    const float* wgt   = (const float*)d_in[6];
    float* out = (float*)d_out;

    char* ws = (char*)d_ws;
    float* JS   = (float*)(ws);                 // 480 f32
    float* Jb   = (float*)(ws + 1920);          // 48 f32
    short* X    = (short*)(ws + 4096);          // [8192][160] bf16   -> 2,621,440 B
    float* rot  = (float*)(ws + 2625536);       // [8192][144] f32    -> 4,718,592 B
    short* Wt3  = (short*)(ws + 7344128);       // [3][832][160] bf16 ->   798,720 B
    float* Abuf = (float*)(ws + 8142848);       // [8192][196] f32    -> 6,422,528 B (end 14,565,376)
    float* jout = out + (size_t)BATCH * NVERT * 3;

    k_pre  <<<528, 64, 0, stream>>>(tmpl, shd, Jreg, JS, Jb);
    k_rodr <<<BATCH * NJ / 256, 256, 0, stream>>>(pose, betas, rot, X);
    k_pack3<<<(3 * NVP * KDIM) / 256, 256, 0, stream>>>(posed, shd, tmpl, Wt3);
    k_chain<<<BATCH / 64, 64, 0, stream>>>(betas, rot, JS, Jb, Abuf, jout);
    k_fused<<<dim3(NVP / 64, BATCH / 64), 256, 0, stream>>>(X, Wt3, Abuf, wgt, out);
}

// Round 10
// 188.588 us; speedup vs baseline: 1.0620x; 1.0620x over previous
//
#include <hip/hip_runtime.h>
#include <hip/hip_bf16.h>

#define BATCH 8192
#define NVERT 778
#define NVP   832     // vertex pad: 13 tiles of 64
#define NJ 16
#define KDIM 160      // 135 pose_feature + 10 betas + 1 const + 14 zero-pad
#define ASTR 196      // Abuf row stride in floats (192 used + 4 pad) = 49 x 16B chunks

typedef __attribute__((ext_vector_type(8))) short short8v;
typedef __attribute__((ext_vector_type(4))) float f32x4;
typedef const __attribute__((address_space(1))) unsigned int* gas1_t;
typedef __attribute__((address_space(3))) unsigned int* las3_t;

static __device__ __forceinline__ unsigned short f2bf(float f) {
    unsigned int u = __float_as_uint(f);
    unsigned int r = (u + 0x7FFFu + ((u >> 16) & 1u)) >> 16;  // RNE
    return (unsigned short)r;
}

// ---------------------------------------------------------------- K0: fold J_regressor
__global__ __launch_bounds__(64) void k_pre(const float* __restrict__ tmpl,
                                            const float* __restrict__ shd,
                                            const float* __restrict__ Jreg,
                                            float* __restrict__ JS,
                                            float* __restrict__ Jb)
{
    int e = blockIdx.x, l = threadIdx.x;
    float s = 0.0f;
    if (e < 480) {
        int j = e / 30, k = (e / 10) % 3, q = e % 10;
        for (int v = l; v < NVERT; v += 64) s += Jreg[j * NVERT + v] * shd[v * 30 + k * 10 + q];
    } else {
        int i = e - 480, j = i / 3, k = i % 3;
        for (int v = l; v < NVERT; v += 64) s += Jreg[j * NVERT + v] * tmpl[v * 3 + k];
    }
#pragma unroll
    for (int off = 32; off > 0; off >>= 1) s += __shfl_down(s, off, 64);
    if (l == 0) { if (e < 480) JS[e] = s; else Jb[e - 480] = s; }
}

// ---------------------------------------------------------------- K1: Rodrigues + X pack
__global__ __launch_bounds__(256) void k_rodr(const float* __restrict__ pose,
                                              const float* __restrict__ betas,
                                              float* __restrict__ rot,
                                              short* __restrict__ X)
{
    int t = blockIdx.x * 256 + threadIdx.x;
    if (t >= BATCH * NJ) return;
    int b = t >> 4, j = t & 15;
    const float* p = pose + b * 48 + j * 3;
    float x = p[0], y = p[1], z = p[2];
    float ax = x + 1e-8f, ay = y + 1e-8f, az = z + 1e-8f;
    float ang = sqrtf(ax * ax + ay * ay + az * az);
    float inv = 1.0f / ang;
    float a = x * inv, bb = y * inv, cc = z * inv;
    float sn = sinf(ang), co = cosf(ang);
    float oc = 1.0f - co;
    float R[9];
    R[0] = 1.0f - oc * (bb * bb + cc * cc);
    R[1] = -sn * cc + oc * a * bb;
    R[2] =  sn * bb + oc * a * cc;
    R[3] =  sn * cc + oc * a * bb;
    R[4] = 1.0f - oc * (a * a + cc * cc);
    R[5] = -sn * a + oc * bb * cc;
    R[6] = -sn * bb + oc * a * cc;
    R[7] =  sn * a + oc * bb * cc;
    R[8] = 1.0f - oc * (a * a + bb * bb);

    float* Rg = rot + b * 144 + j * 9;
#pragma unroll
    for (int m = 0; m < 9; ++m) Rg[m] = R[m];

    short* Xb = X + (size_t)b * KDIM;
    if (j > 0) {
        int base = (j - 1) * 9;
#pragma unroll
        for (int m = 0; m < 9; ++m) {
            float d = (m == 0 || m == 4 || m == 8) ? 1.0f : 0.0f;
            Xb[base + m] = (short)f2bf(R[m] - d);
        }
    } else {
#pragma unroll
        for (int l = 0; l < 10; ++l) Xb[135 + l] = (short)f2bf(betas[b * 10 + l]);
        Xb[145] = (short)0x3F80;  // 1.0 bf16
#pragma unroll
        for (int q = 146; q < 160; ++q) Xb[q] = 0;
    }
}

// ---------------------------------------------------------------- K2: kinematic chain per b
__global__ __launch_bounds__(64) void k_chain(
    const float* __restrict__ betas, const float* __restrict__ rot,
    const float* __restrict__ JS, const float* __restrict__ Jb,
    float* __restrict__ Abuf, float* __restrict__ jout)
{
    int b = blockIdx.x * 64 + threadIdx.x;
    if (b >= BATCH) return;
    float be[10];
#pragma unroll
    for (int l = 0; l < 10; ++l) be[l] = betas[b * 10 + l];

    const float* rb = rot + b * 144;
    float* Ab = Abuf + (size_t)b * ASTR;
    float* jo = jout + b * 48;

    float j0[3];
#pragma unroll
    for (int k = 0; k < 3; ++k) {
        float s = Jb[k];
#pragma unroll
        for (int l = 0; l < 10; ++l) s += JS[k * 10 + l] * be[l];
        j0[k] = s;
    }
    float R0[9];
#pragma unroll
    for (int m = 0; m < 9; ++m) R0[m] = rb[m];

#pragma unroll
    for (int r = 0; r < 3; ++r) {
        Ab[r * 4 + 0] = R0[r * 3 + 0];
        Ab[r * 4 + 1] = R0[r * 3 + 1];
        Ab[r * 4 + 2] = R0[r * 3 + 2];
        Ab[r * 4 + 3] = j0[r] - (R0[r * 3 + 0] * j0[0] + R0[r * 3 + 1] * j0[1] + R0[r * 3 + 2] * j0[2]);
        jo[r] = j0[r];
    }

#pragma unroll
    for (int c = 0; c < 5; ++c) {
        float Gp[12];
#pragma unroll
        for (int r = 0; r < 3; ++r) {
            Gp[r * 4 + 0] = R0[r * 3 + 0];
            Gp[r * 4 + 1] = R0[r * 3 + 1];
            Gp[r * 4 + 2] = R0[r * 3 + 2];
            Gp[r * 4 + 3] = j0[r];
        }
        float jp[3] = { j0[0], j0[1], j0[2] };
#pragma unroll
        for (int s3 = 0; s3 < 3; ++s3) {
            int j = 3 * c + 1 + s3;
            float jj[3];
#pragma unroll
            for (int k = 0; k < 3; ++k) {
                float s = Jb[j * 3 + k];
#pragma unroll
                for (int l = 0; l < 10; ++l) s += JS[(j * 3 + k) * 10 + l] * be[l];
                jj[k] = s;
            }
            float R[9];
#pragma unroll
            for (int m = 0; m < 9; ++m) R[m] = rb[j * 9 + m];
            float rel[3] = { jj[0] - jp[0], jj[1] - jp[1], jj[2] - jp[2] };
            float Gc[12];
#pragma unroll
            for (int r = 0; r < 3; ++r) {
#pragma unroll
                for (int cc = 0; cc < 3; ++cc)
                    Gc[r * 4 + cc] = Gp[r * 4 + 0] * R[cc] + Gp[r * 4 + 1] * R[3 + cc] + Gp[r * 4 + 2] * R[6 + cc];
                Gc[r * 4 + 3] = Gp[r * 4 + 0] * rel[0] + Gp[r * 4 + 1] * rel[1] + Gp[r * 4 + 2] * rel[2] + Gp[r * 4 + 3];
            }
#pragma unroll
            for (int r = 0; r < 3; ++r) {
                Ab[j * 12 + r * 4 + 0] = Gc[r * 4 + 0];
                Ab[j * 12 + r * 4 + 1] = Gc[r * 4 + 1];
                Ab[j * 12 + r * 4 + 2] = Gc[r * 4 + 2];
                Ab[j * 12 + r * 4 + 3] = Gc[r * 4 + 3] - (Gc[r * 4 + 0] * jj[0] + Gc[r * 4 + 1] * jj[1] + Gc[r * 4 + 2] * jj[2]);
                jo[j * 3 + r] = Gc[r * 4 + 3];
            }
#pragma unroll
            for (int m = 0; m < 12; ++m) Gp[m] = Gc[m];
            jp[0] = jj[0]; jp[1] = jj[1]; jp[2] = jj[2];
        }
    }
}

// ---------------------------------------------------------------- K3: pack Wt3 [3][NVP][KDIM] bf16
__global__ __launch_bounds__(256) void k_pack3(const float* __restrict__ posed,
                                               const float* __restrict__ shd,
                                               const float* __restrict__ tmpl,
                                               short* __restrict__ Wt3)
{
    int e = blockIdx.x * 256 + threadIdx.x;   // ((p*NVP + v)*KDIM + k)
    if (e >= 3 * NVP * KDIM) return;
    int k = e % KDIM, pv = e / KDIM;
    int v = pv % NVP, p = pv / NVP;
    float val = 0.0f;
    if (v < NVERT) {
        int n = v * 3 + p;
        if (k < 135)       val = posed[(size_t)k * (NVERT * 3) + n];
        else if (k < 145)  val = shd[v * 30 + p * 10 + (k - 135)];
        else if (k == 145) val = tmpl[n];
    }
    Wt3[e] = (short)f2bf(val);
}

// ---------------------------------------------------------------- K4: fused MFMA GEMM + LBS
// vs round 9 (passing), exactly two deltas, both k_fused-local:
//  (1) w LDS -> w_sT[16][64] (4096 B): total LDS 54,272 = 106x512 -> 3 blocks/CU.
//  (2) XCD swizzle: 1664 = 8 x 208 = 8 x (16 b-tiles x 13 v-tiles) -> each XCD
//      owns 16 whole b-tiles; per-XCD L2 working set ~2MB.
__global__ __launch_bounds__(256, 2) void k_fused(
    const short* __restrict__ X, const short* __restrict__ Wt3,
    const float* __restrict__ Abuf, const float* __restrict__ wgt,
    float* __restrict__ out)
{
    __shared__ __attribute__((aligned(16))) char smem[54272];
    float* A_s  = (float*)smem;                 // [64][196] = 50,176 B
    float* w_sT = (float*)(smem + 50176);       // [16][64]  =  4,096 B

    const int tid = threadIdx.x;
    const int wid = tid >> 6, lane = tid & 63;
    const int lm = lane & 15, lk = lane >> 4;

    int lin = blockIdx.x;
    int swz = (lin & 7) * 208 + (lin >> 3);     // bijective: 8 x 208 = 1664
    int by = swz / 13, bx = swz - by * 13;
    const int v0 = bx * 64;
    const int b0 = by * 64;

    // ---- A_s staging issued NOW (async; drains at the single barrier) ----
    for (int c0 = wid * 64; c0 < 3136; c0 += 256) {
        int c = c0 + lane;
        const float* src = Abuf + (size_t)(b0 + c / 49) * ASTR + (c % 49) * 4;
        __builtin_amdgcn_global_load_lds((gas1_t)(const void*)src,
                                         (las3_t)(void*)(smem + c0 * 16), 16, 0, 0);
    }
    // w_sT fill: [j][v] layout, conflict-free on write and read
    for (int e = tid; e < 1024; e += 256) {
        int j = e >> 6, v = e & 63;
        w_sT[e] = ((v0 + v) < NVERT) ? wgt[(v0 + v) * 16 + j] : 0.0f;
    }

    // ---- MFMA from global: acc[p][vi], K=160 in 5 steps of 32 ----
    f32x4 acc[3][4];
#pragma unroll
    for (int p = 0; p < 3; ++p)
#pragma unroll
        for (int vi = 0; vi < 4; ++vi)
            acc[p][vi] = (f32x4){0.0f, 0.0f, 0.0f, 0.0f};

    const short* Xrow = X + (size_t)(b0 + wid * 16 + lm) * KDIM;
#pragma unroll
    for (int ks = 0; ks < 5; ++ks) {
        int kg = ks * 4 + lk;
        short8v a = *(const short8v*)&Xrow[kg * 8];
        short8v bf[3][4];
#pragma unroll
        for (int p = 0; p < 3; ++p)
#pragma unroll
            for (int vi = 0; vi < 4; ++vi)
                bf[p][vi] = *(const short8v*)&Wt3[(size_t)(p * NVP + v0 + vi * 16 + lm) * KDIM + kg * 8];
#pragma unroll
        for (int p = 0; p < 3; ++p)
#pragma unroll
            for (int vi = 0; vi < 4; ++vi)
                acc[p][vi] = __builtin_amdgcn_mfma_f32_16x16x32_bf16(a, bf[p][vi], acc[p][vi], 0, 0, 0);
    }
    __syncthreads();   // drains staging vmcnt + w_sT lgkmcnt for all waves

    // ---- LBS blend: round-9 loop structure; only wj addressing changed ----
    float o[4][4][3];
#pragma unroll
    for (int r = 0; r < 4; ++r)
#pragma unroll
        for (int vi = 0; vi < 4; ++vi)
            o[r][vi][0] = o[r][vi][1] = o[r][vi][2] = 0.0f;

    for (int j = 0; j < 16; ++j) {
        float wj[4];
#pragma unroll
        for (int vi = 0; vi < 4; ++vi) wj[vi] = w_sT[j * 64 + vi * 16 + lm];
#pragma unroll
        for (int r = 0; r < 4; ++r) {
            const float* Ar = &A_s[(wid * 16 + lk * 4 + r) * ASTR + j * 12];
            f32x4 R0 = *(const f32x4*)(Ar);
            f32x4 R1 = *(const f32x4*)(Ar + 4);
            f32x4 R2 = *(const f32x4*)(Ar + 8);
#pragma unroll
            for (int vi = 0; vi < 4; ++vi) {
                float x = acc[0][vi][r], y = acc[1][vi][r], z = acc[2][vi][r];
                float t0 = fmaf(R0[0], x, fmaf(R0[1], y, fmaf(R0[2], z, R0[3])));
                float t1 = fmaf(R1[0], x, fmaf(R1[1], y, fmaf(R1[2], z, R1[3])));
                float t2 = fmaf(R2[0], x, fmaf(R2[1], y, fmaf(R2[2], z, R2[3])));
                o[r][vi][0] = fmaf(wj[vi], t0, o[r][vi][0]);
                o[r][vi][1] = fmaf(wj[vi], t1, o[r][vi][1]);
                o[r][vi][2] = fmaf(wj[vi], t2, o[r][vi][2]);
            }
        }
    }

    // ---- store: exact round-9 ----
#pragma unroll
    for (int r = 0; r < 4; ++r) {
        int b = b0 + wid * 16 + lk * 4 + r;
#pragma unroll
        for (int vi = 0; vi < 4; ++vi) {
            int v = v0 + vi * 16 + lm;
            if (v < NVERT) {
                float* op = out + ((size_t)b * NVERT + v) * 3;
                op[0] = o[r][vi][0]; op[1] = o[r][vi][1]; op[2] = o[r][vi][2];
            }
        }
    }
}

// ----------------------------------------------------------------
extern "C" void kernel_launch(void* const* d_in, const int* in_sizes, int n_in,
                              void* d_out, int out_size, void* d_ws, size_t ws_size,
                              hipStream_t stream)
{
    (void)in_sizes; (void)n_in; (void)out_size; (void)ws_size;
    const float* betas = (const float*)d_in[0];
    const float* pose  = (const float*)d_in[1];
    const float* tmpl  = (const float*)d_in[2];
    const float* shd   = (const float*)d_in[3];
    const float* posed = (const float*)d_in[4];
    const float* Jreg  = (const float*)d_in[5];
    const float* wgt   = (const float*)d_in[6];
    float* out = (float*)d_out;

    char* ws = (char*)d_ws;
    float* JS   = (float*)(ws);                 // 480 f32
    float* Jb   = (float*)(ws + 1920);          // 48 f32
    short* X    = (short*)(ws + 4096);          // [8192][160] bf16   -> 2,621,440 B
    float* rot  = (float*)(ws + 2625536);       // [8192][144] f32    -> 4,718,592 B
    short* Wt3  = (short*)(ws + 7344128);       // [3][832][160] bf16 ->   798,720 B
    float* Abuf = (float*)(ws + 8142848);       // [8192][196] f32    -> 6,422,528 B (end 14,565,376)
    float* jout = out + (size_t)BATCH * NVERT * 3;

    k_pre  <<<528, 64, 0, stream>>>(tmpl, shd, Jreg, JS, Jb);
    k_rodr <<<BATCH * NJ / 256, 256, 0, stream>>>(pose, betas, rot, X);
    k_pack3<<<(3 * NVP * KDIM) / 256, 256, 0, stream>>>(posed, shd, tmpl, Wt3);
    k_chain<<<BATCH / 64, 64, 0, stream>>>(betas, rot, JS, Jb, Abuf, jout);
    k_fused<<<(NVP / 64) * (BATCH / 64), 256, 0, stream>>>(X, Wt3, Abuf, wgt, out);
}